// Round 1
// baseline (1012.986 us; speedup 1.0000x reference)
//
#include <hip/hip_runtime.h>

// GraphConv: 3-hop COO SpMM over concat(user_embed, item_embed).
// out layout: [N_NODES, NHOPS+1, 64] fp32 (flat = node*256 + hop*64 + j).

#define DFEAT 64

// Write hop-0 slot from embeddings, zero hops 1..3.
// One thread per (node, float4-quad): 16 quads per node.
__global__ void gc_init_out(const float4* __restrict__ user4,
                            const float4* __restrict__ item4,
                            float4* __restrict__ out4,
                            int n_users, int n_nodes) {
    int tid = blockIdx.x * blockDim.x + threadIdx.x;
    int total = n_nodes * 16;
    if (tid >= total) return;
    int node = tid >> 4;
    int q = tid & 15;
    float4 v = (node < n_users) ? user4[(size_t)node * 16 + q]
                                : item4[(size_t)(node - n_users) * 16 + q];
    float4 z = make_float4(0.f, 0.f, 0.f, 0.f);
    float4* p = out4 + (size_t)node * 64 + q;   // node*256 floats / 4
    p[0]  = v;   // hop 0
    p[16] = z;   // hop 1
    p[32] = z;   // hop 2
    p[48] = z;   // hop 3
}

// One wave (64 lanes) per edge; lane j handles feature j.
// Gather out[col, hop-1, j] (coalesced 256B per wave), atomic-scatter into
// out[row, hop, j].
__global__ void gc_spmm_hop(const int* __restrict__ adj_row,
                            const int* __restrict__ adj_col,
                            const float* __restrict__ adj_val,
                            float* __restrict__ out,
                            int hop, int nnz) {
    long long tid = (long long)blockIdx.x * blockDim.x + threadIdx.x;
    int e = (int)(tid >> 6);
    int j = (int)(tid & 63);
    if (e >= nnz) return;
    int r = adj_row[e];
    int c = adj_col[e];
    float v = adj_val[e];
    float x = out[(size_t)c * 256 + (size_t)(hop - 1) * 64 + j];
    unsafeAtomicAdd(&out[(size_t)r * 256 + (size_t)hop * 64 + j], v * x);
}

extern "C" void kernel_launch(void* const* d_in, const int* in_sizes, int n_in,
                              void* d_out, int out_size, void* d_ws, size_t ws_size,
                              hipStream_t stream) {
    const float* user_embed = (const float*)d_in[0];
    const float* item_embed = (const float*)d_in[1];
    const int*   adj_row    = (const int*)d_in[2];
    const int*   adj_col    = (const int*)d_in[3];
    const float* adj_val    = (const float*)d_in[4];
    // d_in[5] = n_users scalar on device; derive on host from sizes instead.
    const int n_users = in_sizes[0] / DFEAT;
    const int n_items = in_sizes[1] / DFEAT;
    const int n_nodes = n_users + n_items;
    const int nnz     = in_sizes[2];
    float* out = (float*)d_out;

    const int threads = 256;

    // Init: hop0 = embeddings, hops 1-3 = 0.
    int init_total = n_nodes * 16;
    int init_blocks = (init_total + threads - 1) / threads;
    hipLaunchKernelGGL(gc_init_out, dim3(init_blocks), dim3(threads), 0, stream,
                       (const float4*)user_embed, (const float4*)item_embed,
                       (float4*)out, n_users, n_nodes);

    // 3 sequential SpMM hops.
    long long spmm_total = (long long)nnz * 64;
    int spmm_blocks = (int)((spmm_total + threads - 1) / threads);
    for (int h = 1; h <= 3; ++h) {
        hipLaunchKernelGGL(gc_spmm_hop, dim3(spmm_blocks), dim3(threads), 0, stream,
                           adj_row, adj_col, adj_val, out, h, nnz);
    }
}

// Round 2
// 809.029 us; speedup vs baseline: 1.2521x; 1.2521x over previous
//
#include <hip/hip_runtime.h>

// GraphConv 3-hop COO SpMM, CSR-rebuilt-per-call (no scatter atomics in hops).
// out layout: [N_NODES, NHOPS+1, 64] fp32 (flat = node*256 + hop*64 + j).

#define DFEAT 64
#define SCAN_TPB 256
#define SCAN_EPB 2048  // 8 elements per thread

// ---------- init: write hop-0 slice from embeddings (hops 1-3 are fully
// overwritten by the CSR hop kernels, so no zeroing needed) ----------
__global__ void gc_init_hop0(const float4* __restrict__ user4,
                             const float4* __restrict__ item4,
                             float4* __restrict__ out4,
                             int n_users, int n_nodes) {
    int tid = blockIdx.x * blockDim.x + threadIdx.x;
    if (tid >= n_nodes * 16) return;
    int node = tid >> 4;
    int q = tid & 15;
    float4 v = (node < n_users) ? user4[(size_t)node * 16 + q]
                                : item4[(size_t)(node - n_users) * 16 + q];
    out4[(size_t)node * 64 + q] = v;   // hop 0 slot
}

// ---------- CSR build ----------
__global__ void gc_hist(const int* __restrict__ row, int* __restrict__ cnt, int nnz) {
    int i = blockIdx.x * blockDim.x + threadIdx.x;
    if (i < nnz) atomicAdd(&cnt[row[i]], 1);
}

// Per-block exclusive scan (2048 elems/block); block totals to bsums.
__global__ void gc_scan1(const int* __restrict__ cnt, int* __restrict__ excl,
                         int* __restrict__ bsums, int n) {
    __shared__ int lds[SCAN_TPB];
    int t = threadIdx.x;
    int base = blockIdx.x * SCAN_EPB + t * 8;
    int v[8];
    int s = 0;
    for (int k = 0; k < 8; ++k) {
        int idx = base + k;
        v[k] = (idx < n) ? cnt[idx] : 0;
        s += v[k];
    }
    lds[t] = s;
    __syncthreads();
    for (int off = 1; off < SCAN_TPB; off <<= 1) {
        int u = (t >= off) ? lds[t - off] : 0;
        __syncthreads();
        lds[t] += u;
        __syncthreads();
    }
    int run = (t > 0) ? lds[t - 1] : 0;
    for (int k = 0; k < 8; ++k) {
        int idx = base + k;
        if (idx < n) excl[idx] = run;
        run += v[k];
    }
    if (t == SCAN_TPB - 1) bsums[blockIdx.x] = lds[SCAN_TPB - 1];
}

// Exclusive scan of block sums (nb <= 256).
__global__ void gc_scan2(int* __restrict__ bsums, int nb) {
    __shared__ int lds[SCAN_TPB];
    int t = threadIdx.x;
    int v = (t < nb) ? bsums[t] : 0;
    lds[t] = v;
    __syncthreads();
    for (int off = 1; off < SCAN_TPB; off <<= 1) {
        int u = (t >= off) ? lds[t - off] : 0;
        __syncthreads();
        lds[t] += u;
        __syncthreads();
    }
    int excl = (t > 0) ? lds[t - 1] : 0;
    if (t < nb) bsums[t] = excl;
}

// Add block offsets; produce row_ptr and a scatter cursor copy.
__global__ void gc_scan3(int* __restrict__ excl, const int* __restrict__ bsums,
                         int* __restrict__ row_ptr, int* __restrict__ cursor,
                         int n, int nnz) {
    int i = blockIdx.x * blockDim.x + threadIdx.x;
    if (i < n) {
        int v = excl[i] + bsums[i / SCAN_EPB];
        row_ptr[i] = v;
        cursor[i] = v;
    }
    if (i == 0) row_ptr[n] = nnz;
}

__global__ void gc_scatter(const int* __restrict__ row, const int* __restrict__ col,
                           const float* __restrict__ val,
                           int* __restrict__ cursor, int* __restrict__ scol,
                           float* __restrict__ sval, int nnz) {
    int i = blockIdx.x * blockDim.x + threadIdx.x;
    if (i >= nnz) return;
    int r = row[i];
    int pos = atomicAdd(&cursor[r], 1);
    scol[pos] = col[i];
    sval[pos] = val[i];
}

// ---------- hop: one wave per destination row, lane j = feature j ----------
__global__ void gc_spmm_csr(const int* __restrict__ rp, const int* __restrict__ scol,
                            const float* __restrict__ sval,
                            float* __restrict__ out, int hop, int n_nodes) {
    int tid = blockIdx.x * blockDim.x + threadIdx.x;
    int r = tid >> 6;
    int lane = tid & 63;
    if (r >= n_nodes) return;
    int beg = rp[r], end = rp[r + 1];
    float acc = 0.f;
    size_t src_base = (size_t)(hop - 1) * 64 + lane;
    for (int e = beg; e < end; ++e) {
        int c = scol[e];
        float v = sval[e];
        acc += v * out[(size_t)c * 256 + src_base];
    }
    out[(size_t)r * 256 + (size_t)hop * 64 + lane] = acc;
}

// ---------- fallback (ws too small): round-1 atomic version ----------
__global__ void gc_init_out_full(const float4* __restrict__ user4,
                                 const float4* __restrict__ item4,
                                 float4* __restrict__ out4,
                                 int n_users, int n_nodes) {
    int tid = blockIdx.x * blockDim.x + threadIdx.x;
    if (tid >= n_nodes * 16) return;
    int node = tid >> 4;
    int q = tid & 15;
    float4 v = (node < n_users) ? user4[(size_t)node * 16 + q]
                                : item4[(size_t)(node - n_users) * 16 + q];
    float4 z = make_float4(0.f, 0.f, 0.f, 0.f);
    float4* p = out4 + (size_t)node * 64 + q;
    p[0] = v; p[16] = z; p[32] = z; p[48] = z;
}

__global__ void gc_spmm_atomic(const int* __restrict__ adj_row,
                               const int* __restrict__ adj_col,
                               const float* __restrict__ adj_val,
                               float* __restrict__ out, int hop, int nnz) {
    long long tid = (long long)blockIdx.x * blockDim.x + threadIdx.x;
    int e = (int)(tid >> 6);
    int j = (int)(tid & 63);
    if (e >= nnz) return;
    int r = adj_row[e];
    int c = adj_col[e];
    float v = adj_val[e];
    float x = out[(size_t)c * 256 + (size_t)(hop - 1) * 64 + j];
    unsafeAtomicAdd(&out[(size_t)r * 256 + (size_t)hop * 64 + j], v * x);
}

extern "C" void kernel_launch(void* const* d_in, const int* in_sizes, int n_in,
                              void* d_out, int out_size, void* d_ws, size_t ws_size,
                              hipStream_t stream) {
    const float* user_embed = (const float*)d_in[0];
    const float* item_embed = (const float*)d_in[1];
    const int*   adj_row    = (const int*)d_in[2];
    const int*   adj_col    = (const int*)d_in[3];
    const float* adj_val    = (const float*)d_in[4];
    const int n_users = in_sizes[0] / DFEAT;
    const int n_items = in_sizes[1] / DFEAT;
    const int n_nodes = n_users + n_items;
    const int nnz     = in_sizes[2];
    float* out = (float*)d_out;

    const int threads = 256;

    // ---- workspace carve-up ----
    size_t off = 0;
    auto carve = [&](size_t bytes) { size_t o = off; off = (off + bytes + 255) & ~(size_t)255; return o; };
    size_t o_cnt    = carve((size_t)n_nodes * 4);
    size_t o_rowptr = carve((size_t)(n_nodes + 1) * 4);
    size_t o_cursor = carve((size_t)n_nodes * 4);
    size_t o_bsums  = carve(256 * 4);
    size_t o_scol   = carve((size_t)nnz * 4);
    size_t o_sval   = carve((size_t)nnz * 4);
    size_t needed = off;

    if (ws_size < needed) {
        // Fallback: atomic scatter version.
        int init_blocks = (n_nodes * 16 + threads - 1) / threads;
        hipLaunchKernelGGL(gc_init_out_full, dim3(init_blocks), dim3(threads), 0, stream,
                           (const float4*)user_embed, (const float4*)item_embed,
                           (float4*)out, n_users, n_nodes);
        long long spmm_total = (long long)nnz * 64;
        int spmm_blocks = (int)((spmm_total + threads - 1) / threads);
        for (int h = 1; h <= 3; ++h) {
            hipLaunchKernelGGL(gc_spmm_atomic, dim3(spmm_blocks), dim3(threads), 0, stream,
                               adj_row, adj_col, adj_val, out, h, nnz);
        }
        return;
    }

    char* ws = (char*)d_ws;
    int*   cnt    = (int*)(ws + o_cnt);
    int*   rowptr = (int*)(ws + o_rowptr);
    int*   cursor = (int*)(ws + o_cursor);
    int*   bsums  = (int*)(ws + o_bsums);
    int*   scol   = (int*)(ws + o_scol);
    float* sval   = (float*)(ws + o_sval);

    // ---- init hop-0 slice (independent of CSR build) ----
    int init_blocks = (n_nodes * 16 + threads - 1) / threads;
    hipLaunchKernelGGL(gc_init_hop0, dim3(init_blocks), dim3(threads), 0, stream,
                       (const float4*)user_embed, (const float4*)item_embed,
                       (float4*)out, n_users, n_nodes);

    // ---- CSR build ----
    hipMemsetAsync(cnt, 0, (size_t)n_nodes * 4, stream);
    int hist_blocks = (nnz + threads - 1) / threads;
    hipLaunchKernelGGL(gc_hist, dim3(hist_blocks), dim3(threads), 0, stream,
                       adj_row, cnt, nnz);
    int nb = (n_nodes + SCAN_EPB - 1) / SCAN_EPB;   // 245 for 500k
    hipLaunchKernelGGL(gc_scan1, dim3(nb), dim3(SCAN_TPB), 0, stream,
                       cnt, rowptr, bsums, n_nodes);
    hipLaunchKernelGGL(gc_scan2, dim3(1), dim3(SCAN_TPB), 0, stream, bsums, nb);
    int scan3_blocks = (n_nodes + threads - 1) / threads;
    hipLaunchKernelGGL(gc_scan3, dim3(scan3_blocks), dim3(threads), 0, stream,
                       rowptr, bsums, rowptr, cursor, n_nodes, nnz);
    hipLaunchKernelGGL(gc_scatter, dim3(hist_blocks), dim3(threads), 0, stream,
                       adj_row, adj_col, adj_val, cursor, scol, sval, nnz);

    // ---- 3 CSR hops, wave per row ----
    long long hop_threads = (long long)n_nodes * 64;
    int hop_blocks = (int)((hop_threads + threads - 1) / threads);
    for (int h = 1; h <= 3; ++h) {
        hipLaunchKernelGGL(gc_spmm_csr, dim3(hop_blocks), dim3(threads), 0, stream,
                           rowptr, scol, sval, out, h, n_nodes);
    }
}

// Round 4
// 497.336 us; speedup vs baseline: 2.0368x; 1.6267x over previous
//
#include <hip/hip_runtime.h>

// GraphConv 3-hop SpMM, CSR rebuilt per call; 4 rows/wave float4 hop kernel.
// out layout: [N_NODES, 4, 64] fp32 (flat = node*256 + hop*64 + j).

#define DFEAT 64
#define SCAN_TPB 256
#define SCAN_EPB 2048  // 8 elements per thread

typedef float f32x4 __attribute__((ext_vector_type(4)));  // native vec for NT store

// ---------- init: write hop-0 slice from embeddings ----------
__global__ void gc_init_hop0(const float4* __restrict__ user4,
                             const float4* __restrict__ item4,
                             float4* __restrict__ out4,
                             int n_users, int n_nodes) {
    int tid = blockIdx.x * blockDim.x + threadIdx.x;
    if (tid >= n_nodes * 16) return;
    int node = tid >> 4;
    int q = tid & 15;
    float4 v = (node < n_users) ? user4[(size_t)node * 16 + q]
                                : item4[(size_t)(node - n_users) * 16 + q];
    out4[(size_t)node * 64 + q] = v;   // hop 0 slot
}

// ---------- CSR build ----------
__global__ void gc_hist(const int* __restrict__ row, int* __restrict__ cnt, int nnz) {
    int i = blockIdx.x * blockDim.x + threadIdx.x;
    if (i < nnz) atomicAdd(&cnt[row[i]], 1);
}

__global__ void gc_scan1(const int* __restrict__ cnt, int* __restrict__ excl,
                         int* __restrict__ bsums, int n) {
    __shared__ int lds[SCAN_TPB];
    int t = threadIdx.x;
    int base = blockIdx.x * SCAN_EPB + t * 8;
    int v[8];
    int s = 0;
    for (int k = 0; k < 8; ++k) {
        int idx = base + k;
        v[k] = (idx < n) ? cnt[idx] : 0;
        s += v[k];
    }
    lds[t] = s;
    __syncthreads();
    for (int off = 1; off < SCAN_TPB; off <<= 1) {
        int u = (t >= off) ? lds[t - off] : 0;
        __syncthreads();
        lds[t] += u;
        __syncthreads();
    }
    int run = (t > 0) ? lds[t - 1] : 0;
    for (int k = 0; k < 8; ++k) {
        int idx = base + k;
        if (idx < n) excl[idx] = run;
        run += v[k];
    }
    if (t == SCAN_TPB - 1) bsums[blockIdx.x] = lds[SCAN_TPB - 1];
}

__global__ void gc_scan2(int* __restrict__ bsums, int nb) {
    __shared__ int lds[SCAN_TPB];
    int t = threadIdx.x;
    int v = (t < nb) ? bsums[t] : 0;
    lds[t] = v;
    __syncthreads();
    for (int off = 1; off < SCAN_TPB; off <<= 1) {
        int u = (t >= off) ? lds[t - off] : 0;
        __syncthreads();
        lds[t] += u;
        __syncthreads();
    }
    int excl = (t > 0) ? lds[t - 1] : 0;
    if (t < nb) bsums[t] = excl;
}

__global__ void gc_scan3(int* __restrict__ excl, const int* __restrict__ bsums,
                         int* __restrict__ row_ptr, int* __restrict__ cursor,
                         int n, int nnz) {
    int i = blockIdx.x * blockDim.x + threadIdx.x;
    if (i < n) {
        int v = excl[i] + bsums[i / SCAN_EPB];
        row_ptr[i] = v;
        cursor[i] = v;
    }
    if (i == 0) row_ptr[n] = nnz;
}

// Scatter edges into CSR order, packing (col,val) into float2 (8B store).
__global__ void gc_scatter(const int* __restrict__ row, const int* __restrict__ col,
                           const float* __restrict__ val,
                           int* __restrict__ cursor, float2* __restrict__ edges,
                           int nnz) {
    int i = blockIdx.x * blockDim.x + threadIdx.x;
    if (i >= nnz) return;
    int r = row[i];
    int pos = atomicAdd(&cursor[r], 1);
    edges[pos] = make_float2(__int_as_float(col[i]), val[i]);
}

// ---------- hop: 16 lanes (float4 each) per row; 4 rows per wave ----------
__global__ void gc_spmm_csr4(const int* __restrict__ rp,
                             const float2* __restrict__ edges,
                             float* __restrict__ out, int hop, int n_nodes) {
    int tid = blockIdx.x * blockDim.x + threadIdx.x;
    int q = tid & 15;           // float4 quad within the row
    int r = tid >> 4;           // one row per 16 lanes
    if (r >= n_nodes) return;
    int beg = rp[r], end = rp[r + 1];
    float4 acc = make_float4(0.f, 0.f, 0.f, 0.f);
    size_t src_slice = (size_t)(hop - 1) * 64;
    for (int e = beg; e < end; ++e) {
        float2 ed = edges[e];
        int c = __float_as_int(ed.x);
        float v = ed.y;
        const float4* s = (const float4*)(out + (size_t)c * 256 + src_slice);
        float4 x = s[q];
        acc.x += v * x.x; acc.y += v * x.y; acc.z += v * x.z; acc.w += v * x.w;
    }
    float* dst = out + (size_t)r * 256 + (size_t)hop * 64;
    if (hop == 3) {
        f32x4 nv = {acc.x, acc.y, acc.z, acc.w};
        __builtin_nontemporal_store(nv, (f32x4*)dst + q);  // slice 3 never re-read
    } else {
        ((float4*)dst)[q] = acc;
    }
}

// ---------- fallback (ws too small): atomic scatter version ----------
__global__ void gc_init_out_full(const float4* __restrict__ user4,
                                 const float4* __restrict__ item4,
                                 float4* __restrict__ out4,
                                 int n_users, int n_nodes) {
    int tid = blockIdx.x * blockDim.x + threadIdx.x;
    if (tid >= n_nodes * 16) return;
    int node = tid >> 4;
    int q = tid & 15;
    float4 v = (node < n_users) ? user4[(size_t)node * 16 + q]
                                : item4[(size_t)(node - n_users) * 16 + q];
    float4 z = make_float4(0.f, 0.f, 0.f, 0.f);
    float4* p = out4 + (size_t)node * 64 + q;
    p[0] = v; p[16] = z; p[32] = z; p[48] = z;
}

__global__ void gc_spmm_atomic(const int* __restrict__ adj_row,
                               const int* __restrict__ adj_col,
                               const float* __restrict__ adj_val,
                               float* __restrict__ out, int hop, int nnz) {
    long long tid = (long long)blockIdx.x * blockDim.x + threadIdx.x;
    int e = (int)(tid >> 6);
    int j = (int)(tid & 63);
    if (e >= nnz) return;
    int r = adj_row[e];
    int c = adj_col[e];
    float v = adj_val[e];
    float x = out[(size_t)c * 256 + (size_t)(hop - 1) * 64 + j];
    unsafeAtomicAdd(&out[(size_t)r * 256 + (size_t)hop * 64 + j], v * x);
}

extern "C" void kernel_launch(void* const* d_in, const int* in_sizes, int n_in,
                              void* d_out, int out_size, void* d_ws, size_t ws_size,
                              hipStream_t stream) {
    const float* user_embed = (const float*)d_in[0];
    const float* item_embed = (const float*)d_in[1];
    const int*   adj_row    = (const int*)d_in[2];
    const int*   adj_col    = (const int*)d_in[3];
    const float* adj_val    = (const float*)d_in[4];
    const int n_users = in_sizes[0] / DFEAT;
    const int n_items = in_sizes[1] / DFEAT;
    const int n_nodes = n_users + n_items;
    const int nnz     = in_sizes[2];
    float* out = (float*)d_out;

    const int threads = 256;

    // ---- workspace carve-up ----
    size_t off = 0;
    auto carve = [&](size_t bytes) { size_t o = off; off = (off + bytes + 255) & ~(size_t)255; return o; };
    size_t o_cnt    = carve((size_t)n_nodes * 4);
    size_t o_rowptr = carve((size_t)(n_nodes + 1) * 4);
    size_t o_cursor = carve((size_t)n_nodes * 4);
    size_t o_bsums  = carve(256 * 4);
    size_t o_edges  = carve((size_t)nnz * 8);
    size_t needed = off;

    if (ws_size < needed) {
        int init_blocks = (n_nodes * 16 + threads - 1) / threads;
        hipLaunchKernelGGL(gc_init_out_full, dim3(init_blocks), dim3(threads), 0, stream,
                           (const float4*)user_embed, (const float4*)item_embed,
                           (float4*)out, n_users, n_nodes);
        long long spmm_total = (long long)nnz * 64;
        int spmm_blocks = (int)((spmm_total + threads - 1) / threads);
        for (int h = 1; h <= 3; ++h) {
            hipLaunchKernelGGL(gc_spmm_atomic, dim3(spmm_blocks), dim3(threads), 0, stream,
                               adj_row, adj_col, adj_val, out, h, nnz);
        }
        return;
    }

    char* ws = (char*)d_ws;
    int*    cnt    = (int*)(ws + o_cnt);
    int*    rowptr = (int*)(ws + o_rowptr);
    int*    cursor = (int*)(ws + o_cursor);
    int*    bsums  = (int*)(ws + o_bsums);
    float2* edges  = (float2*)(ws + o_edges);

    // ---- init hop-0 slice ----
    int init_blocks = (n_nodes * 16 + threads - 1) / threads;
    hipLaunchKernelGGL(gc_init_hop0, dim3(init_blocks), dim3(threads), 0, stream,
                       (const float4*)user_embed, (const float4*)item_embed,
                       (float4*)out, n_users, n_nodes);

    // ---- CSR build ----
    (void)hipMemsetAsync(cnt, 0, (size_t)n_nodes * 4, stream);
    int hist_blocks = (nnz + threads - 1) / threads;
    hipLaunchKernelGGL(gc_hist, dim3(hist_blocks), dim3(threads), 0, stream,
                       adj_row, cnt, nnz);
    int nb = (n_nodes + SCAN_EPB - 1) / SCAN_EPB;
    hipLaunchKernelGGL(gc_scan1, dim3(nb), dim3(SCAN_TPB), 0, stream,
                       cnt, rowptr, bsums, n_nodes);
    hipLaunchKernelGGL(gc_scan2, dim3(1), dim3(SCAN_TPB), 0, stream, bsums, nb);
    int scan3_blocks = (n_nodes + threads - 1) / threads;
    hipLaunchKernelGGL(gc_scan3, dim3(scan3_blocks), dim3(threads), 0, stream,
                       rowptr, bsums, rowptr, cursor, n_nodes, nnz);
    hipLaunchKernelGGL(gc_scatter, dim3(hist_blocks), dim3(threads), 0, stream,
                       adj_row, adj_col, adj_val, cursor, edges, nnz);

    // ---- 3 CSR hops, 16 lanes per row ----
    long long hop_threads = (long long)n_nodes * 16;
    int hop_blocks = (int)((hop_threads + threads - 1) / threads);
    for (int h = 1; h <= 3; ++h) {
        hipLaunchKernelGGL(gc_spmm_csr4, dim3(hop_blocks), dim3(threads), 0, stream,
                           rowptr, edges, out, h, n_nodes);
    }
}